// Round 8
// baseline (133.907 us; speedup 1.0000x reference)
//
#include <hip/hip_runtime.h>
#include <hip/hip_bf16.h>
#include <stdint.h>

// MahalanobisEnsembleLoss: out = sum_l w[l] * mean_n( v^T M_l v ),  v = F[l,n,:] - MEAN[l,idx[n],:]
// R8 decomposition (asymmetry-correct):  MS = M + M^T (fp16)
//   q_n = 0.5 f^T MS f  -  f . g[idx_n]  +  s[idx_n]
//   g[c] = MS . mean[c]  (fp16 table),  s[c] = 0.5 mean[c] . g[c]  (fp32 table)
// Main kernel = pure f^T MS f GEMM on F (fp16 MFMA), no gather/subtract in staging.
// 512thr/8-wave blocks, BN=64, <=128 unified regs -> 2 blocks/CU co-resident.
#define LDIM 4
#define NDIM 16384
#define DDIM 512
#define CDIM 1000
#define BN 64

// ---- workspace layout (bytes) ----
#define MS_ELEMS ((size_t)LDIM * DDIM * DDIM)
#define GH_OFF   (MS_ELEMS * 2)
#define GH_ELEMS ((size_t)LDIM * CDIM * DDIM)
#define SS_OFF   (GH_OFF + GH_ELEMS * 2)
#define SS_FLOATS ((size_t)LDIM * 1024)
#define WS_NEED  (SS_OFF + SS_FLOATS * 4)   // ~5.92 MiB

typedef __attribute__((ext_vector_type(8))) _Float16 f16x8;
typedef __attribute__((ext_vector_type(4))) float f32x4;

__device__ __forceinline__ unsigned short f2h(float x) {
  union { _Float16 h; unsigned short u; } c; c.h = (_Float16)x; return c.u;
}
__device__ __forceinline__ float h2f(unsigned short u) {
  union { unsigned short u; _Float16 h; } c; c.u = u; return (float)c.h;
}
__device__ __forceinline__ f16x8 cvt8(float4 a, float4 b) {
  f16x8 p;
  p[0] = (_Float16)a.x; p[1] = (_Float16)a.y; p[2] = (_Float16)a.z; p[3] = (_Float16)a.w;
  p[4] = (_Float16)b.x; p[5] = (_Float16)b.y; p[6] = (_Float16)b.z; p[7] = (_Float16)b.w;
  return p;
}

// LDS tile [64 rows][512 e] fp16, row stride 1024 B, 16B granule g=(e>>3) XOR'ed with row&7:
//   byte(row,e) = row*1024 + (((e>>3) ^ (row&7))<<4) + (e&7)*2
#define LDS_MAIN (65536 + 256 + 256 + 32)   // VH | ids[64] | svals[64] | red[8]
#define LDS_PREP 65536

// K0: MS = fp16(M + M^T). Coalesced row read + strided transposed read (R1-validated).
extern "C" __global__ void mel_mconv(const float* __restrict__ IC,
                                     unsigned short* __restrict__ MS) {
  size_t i4 = (size_t)blockIdx.x * 256 + threadIdx.x;  // covers L*D*D/4
  size_t base = i4 * 4;
  int l = (int)(base >> 18);
  int rem = (int)(base & 262143);
  int e = rem & 511;
  int d = rem >> 9;
  float4 v = *(const float4*)(IC + base);
  const float* icl = IC + ((size_t)l << 18);
  float t0 = icl[(size_t)(e + 0) * DDIM + d];
  float t1 = icl[(size_t)(e + 1) * DDIM + d];
  float t2 = icl[(size_t)(e + 2) * DDIM + d];
  float t3 = icl[(size_t)(e + 3) * DDIM + d];
  *(ushort4*)(MS + base) = make_ushort4(f2h(v.x + t0), f2h(v.y + t1),
                                        f2h(v.z + t2), f2h(v.w + t3));
}

// K1: G[l,c,:] = fp16(MS . mean[l,c,:]), S[l,c] = 0.5 * meanh . G. 64 blocks x 512 thr.
extern "C" __global__ __launch_bounds__(512, 2)
void mel_prep(const float* __restrict__ MEAN, const unsigned short* __restrict__ MS,
              unsigned short* __restrict__ GH, float* __restrict__ SS) {
  extern __shared__ __align__(16) char lds[];
  const int t = threadIdx.x, lane = t & 63, w = t >> 6;
  const int l = blockIdx.x & 3, ct = blockIdx.x >> 2;
  const int row0 = ct * 64;
  const int col0 = w * 64, lrow = lane & 15, lkg = lane >> 4;
  const int lke = lkg << 3;

  {  // stage all 8 chunks of mean rows as fp16 (rows >= CDIM -> 0)
    const int srow = t >> 3;
    const int grow = row0 + srow;
    const float* mr = MEAN + ((size_t)l * CDIM + grow) * DDIM + ((t & 7) << 3);
    const int swb = srow * 1024 + (((t & 7) ^ (srow & 7)) << 4);
    const float4 z4 = {0.f, 0.f, 0.f, 0.f};
    for (int c = 0; c < 8; ++c) {
      float4 x = z4, y = z4;
      if (grow < CDIM) { x = *(const float4*)(mr + c * 64); y = *(const float4*)(mr + c * 64 + 4); }
      *(f16x8*)(lds + swb + c * 128) = cvt8(x, y);
    }
  }
  __syncthreads();

  const unsigned short* bw = MS + (size_t)l * DDIM * DDIM + (size_t)(col0 + lrow) * DDIM + lke;
  f32x4 acc[4][4];
#pragma unroll
  for (int i = 0; i < 4; ++i)
#pragma unroll
    for (int j = 0; j < 4; ++j) acc[i][j] = {0.f, 0.f, 0.f, 0.f};

  for (int c = 0; c < 8; ++c) {
#pragma unroll
    for (int ks = 0; ks < 2; ++ks) {
      const unsigned short* bc = bw + c * 64 + ks * 32;
      f16x8 b0 = *(const f16x8*)(bc);
      f16x8 b1 = *(const f16x8*)(bc + 16 * DDIM);
      f16x8 b2 = *(const f16x8*)(bc + 32 * DDIM);
      f16x8 b3 = *(const f16x8*)(bc + 48 * DDIM);
      const int xo = c * 128 + ((((ks << 2) + lkg) ^ (lrow & 7)) << 4);
      f16x8 a0 = *(const f16x8*)(lds + lrow * 1024 + xo);
      f16x8 a1 = *(const f16x8*)(lds + (16 + lrow) * 1024 + xo);
      f16x8 a2 = *(const f16x8*)(lds + (32 + lrow) * 1024 + xo);
      f16x8 a3 = *(const f16x8*)(lds + (48 + lrow) * 1024 + xo);
#pragma unroll
      for (int nf = 0; nf < 4; ++nf) {
        f16x8 a = nf == 0 ? a0 : nf == 1 ? a1 : nf == 2 ? a2 : a3;
        acc[nf][0] = __builtin_amdgcn_mfma_f32_16x16x32_f16(a, b0, acc[nf][0], 0, 0, 0);
        acc[nf][1] = __builtin_amdgcn_mfma_f32_16x16x32_f16(a, b1, acc[nf][1], 0, 0, 0);
        acc[nf][2] = __builtin_amdgcn_mfma_f32_16x16x32_f16(a, b2, acc[nf][2], 0, 0, 0);
        acc[nf][3] = __builtin_amdgcn_mfma_f32_16x16x32_f16(a, b3, acc[nf][3], 0, 0, 0);
      }
    }
  }

  // store G (fp16) + per-row S partials (S gets the 0.5 factor)
#pragma unroll
  for (int nf = 0; nf < 4; ++nf)
#pragma unroll
    for (int r = 0; r < 4; ++r) {
      const int nloc = nf * 16 + lkg * 4 + r;
      const int grow = row0 + nloc;
      float sp = 0.f;
#pragma unroll
      for (int df = 0; df < 4; ++df) {
        const int dcol = col0 + df * 16 + lrow;
        const float av = acc[nf][df][r];
        const float mh = h2f(*(const unsigned short*)(
            lds + nloc * 1024 + (((dcol >> 3) ^ (nloc & 7)) << 4) + (dcol & 7) * 2));
        sp += mh * av;
        if (grow < CDIM) GH[((size_t)l * CDIM + grow) * DDIM + dcol] = f2h(av);
      }
      sp += __shfl_xor(sp, 1); sp += __shfl_xor(sp, 2);
      sp += __shfl_xor(sp, 4); sp += __shfl_xor(sp, 8);
      if (lrow == 0 && grow < CDIM) atomicAdd(SS + l * 1024 + grow, 0.5f * sp);
    }
}

// K2 main: pure f^T MS f GEMM + epilogue q = sum fh*(0.5*acc - gh) + s[idx].
// 8 waves: wave = all 64 rows x 64 cols. 2 blocks/CU co-resident (<=128 regs, 64.5KB LDS).
extern "C" __global__ __launch_bounds__(512, 4)
void mel_main(const float* __restrict__ F, const float* __restrict__ W,
              const int* __restrict__ IDX, const unsigned short* __restrict__ MS,
              const unsigned short* __restrict__ GH, const float* __restrict__ SS,
              float* __restrict__ OUT) {
  extern __shared__ __align__(16) char lds[];
  int* ids = (int*)(lds + 65536);
  float* svals = (float*)(lds + 65536 + 256);
  float* red = (float*)(lds + 65536 + 512);
  const int t = threadIdx.x, lane = t & 63, w = t >> 6;
  const int bid = blockIdx.x, xcd = bid & 7, l = xcd >> 1;
  const int bx = ((bid >> 3) << 1) + (xcd & 1);
  const int n0 = bx * BN;
  const int col0 = w * 64, lrow = lane & 15, lkg = lane >> 4;
  const int lke = lkg << 3;

  if (t < 64) {
    const int cc = IDX[n0 + t];
    ids[t] = cc;
    svals[t] = SS[l * 1024 + cc];
  }

  // staging: thread t owns row t>>3, 8 floats at e = (t&7)*8 within each 64-chunk
  const float* fr = F + ((size_t)l * NDIM + n0 + (t >> 3)) * DDIM + ((t & 7) << 3);
  const int swb = (t >> 3) * 1024 + (((t & 7) ^ ((t >> 3) & 7)) << 4);
  {  // prologue: chunk 0
    float4 x = *(const float4*)(fr);
    float4 y = *(const float4*)(fr + 4);
    *(f16x8*)(lds + swb) = cvt8(x, y);
  }
  __syncthreads();

  const unsigned short* bw = MS + (size_t)l * DDIM * DDIM + (size_t)(col0 + lrow) * DDIM + lke;
  f32x4 acc[4][4];
#pragma unroll
  for (int i = 0; i < 4; ++i)
#pragma unroll
    for (int j = 0; j < 4; ++j) acc[i][j] = {0.f, 0.f, 0.f, 0.f};

  for (int c = 0; c < 8; ++c) {
    float4 nx, ny;
    if (c < 7) {  // prefetch next F chunk (consumed after MFMAs)
      nx = *(const float4*)(fr + (c + 1) * 64);
      ny = *(const float4*)(fr + (c + 1) * 64 + 4);
    }
#pragma unroll
    for (int ks = 0; ks < 2; ++ks) {
      const unsigned short* bc = bw + c * 64 + ks * 32;
      f16x8 b0 = *(const f16x8*)(bc);
      f16x8 b1 = *(const f16x8*)(bc + 16 * DDIM);
      f16x8 b2 = *(const f16x8*)(bc + 32 * DDIM);
      f16x8 b3 = *(const f16x8*)(bc + 48 * DDIM);
      const int xo = c * 128 + ((((ks << 2) + lkg) ^ (lrow & 7)) << 4);
      f16x8 a0 = *(const f16x8*)(lds + lrow * 1024 + xo);
      f16x8 a1 = *(const f16x8*)(lds + (16 + lrow) * 1024 + xo);
      f16x8 a2 = *(const f16x8*)(lds + (32 + lrow) * 1024 + xo);
      f16x8 a3 = *(const f16x8*)(lds + (48 + lrow) * 1024 + xo);
#pragma unroll
      for (int nf = 0; nf < 4; ++nf) {
        f16x8 a = nf == 0 ? a0 : nf == 1 ? a1 : nf == 2 ? a2 : a3;
        acc[nf][0] = __builtin_amdgcn_mfma_f32_16x16x32_f16(a, b0, acc[nf][0], 0, 0, 0);
        acc[nf][1] = __builtin_amdgcn_mfma_f32_16x16x32_f16(a, b1, acc[nf][1], 0, 0, 0);
        acc[nf][2] = __builtin_amdgcn_mfma_f32_16x16x32_f16(a, b2, acc[nf][2], 0, 0, 0);
        acc[nf][3] = __builtin_amdgcn_mfma_f32_16x16x32_f16(a, b3, acc[nf][3], 0, 0, 0);
      }
    }
    if (c < 7) *(f16x8*)(lds + swb + (c + 1) * 128) = cvt8(nx, ny);
    __syncthreads();
  }

  // epilogue: q = sum_d fh*(0.5*acc - gh)  (+ s[idx] once per row, wave 0)
  const unsigned short* gh_l = GH + (size_t)l * CDIM * DDIM;
  float tsum = 0.f;
#pragma unroll
  for (int nf = 0; nf < 4; ++nf)
#pragma unroll
    for (int r = 0; r < 4; ++r) {
      const int row = nf * 16 + lkg * 4 + r;
      const unsigned short* gp = gh_l + (size_t)ids[row] * DDIM;
#pragma unroll
      for (int df = 0; df < 4; ++df) {
        const int dcol = col0 + df * 16 + lrow;
        const float fh = h2f(*(const unsigned short*)(
            lds + row * 1024 + (((dcol >> 3) ^ (row & 7)) << 4) + (dcol & 7) * 2));
        const float gh = h2f(gp[dcol]);
        tsum += fh * (0.5f * acc[nf][df][r] - gh);
      }
      if (w == 0 && lrow == 0) tsum += svals[row];
    }
#pragma unroll
  for (int off = 32; off > 0; off >>= 1) tsum += __shfl_down(tsum, off);
  __syncthreads();
  if (lane == 0) red[w] = tsum;
  __syncthreads();
  if (t == 0) {
    float ssum = 0.f;
#pragma unroll
    for (int i = 0; i < 8; ++i) ssum += red[i];
    atomicAdd(OUT, ssum * (W[l] / (float)NDIM));
  }
}

// Correct-but-slow fp32 fallback (only if ws_size < WS_NEED).
extern "C" __global__ void mel_fallback(const float* __restrict__ F,
                                        const float* __restrict__ MEAN,
                                        const float* __restrict__ IC,
                                        const float* __restrict__ W,
                                        const int* __restrict__ IDX,
                                        float* __restrict__ OUT) {
  __shared__ float v[8][DDIM];
  __shared__ float red[256];
  const int t = threadIdx.x;
  const int l = blockIdx.y;
  const int n0 = blockIdx.x * 8;
  for (int i = t; i < 8 * DDIM; i += 256) {
    int n = i >> 9, e = i & 511;
    int c = IDX[n0 + n];
    v[n][e] = F[((size_t)l * NDIM + n0 + n) * DDIM + e] -
              MEAN[((size_t)l * CDIM + c) * DDIM + e];
  }
  __syncthreads();
  const float* icl = IC + ((size_t)l << 18);
  float part = 0.f;
  for (int rep = 0; rep < 2; ++rep) {
    int d = t + rep * 256;
    float s[8];
#pragma unroll
    for (int j = 0; j < 8; ++j) s[j] = 0.f;
    for (int e = 0; e < DDIM; ++e) {
      float m = icl[(size_t)d * DDIM + e];
#pragma unroll
      for (int j = 0; j < 8; ++j) s[j] += m * v[j][e];
    }
#pragma unroll
    for (int j = 0; j < 8; ++j) part += v[j][d] * s[j];
  }
  red[t] = part;
  __syncthreads();
  for (int o = 128; o > 0; o >>= 1) {
    if (t < o) red[t] += red[t + o];
    __syncthreads();
  }
  if (t == 0) atomicAdd(OUT, red[0] * (W[l] / (float)NDIM));
}

extern "C" void kernel_launch(void* const* d_in, const int* in_sizes, int n_in,
                              void* d_out, int out_size, void* d_ws, size_t ws_size,
                              hipStream_t stream) {
  const float* F = (const float*)d_in[0];
  const float* MEAN = (const float*)d_in[1];
  const float* IC = (const float*)d_in[2];
  const float* W = (const float*)d_in[3];
  const int* IDX = (const int*)d_in[4];
  float* OUT = (float*)d_out;

  hipMemsetAsync(d_out, 0, sizeof(float) * (size_t)out_size, stream);

  if (ws_size >= WS_NEED) {
    unsigned short* MSp = (unsigned short*)d_ws;
    unsigned short* GHp = (unsigned short*)((char*)d_ws + GH_OFF);
    float* SSp = (float*)((char*)d_ws + SS_OFF);
    hipMemsetAsync(SSp, 0, SS_FLOATS * 4, stream);
    mel_mconv<<<dim3(1024), dim3(256), 0, stream>>>(IC, MSp);
    (void)hipFuncSetAttribute(reinterpret_cast<const void*>(mel_prep),
                              hipFuncAttributeMaxDynamicSharedMemorySize, LDS_PREP);
    mel_prep<<<dim3(64), dim3(512), LDS_PREP, stream>>>(MEAN, MSp, GHp, SSp);
    (void)hipFuncSetAttribute(reinterpret_cast<const void*>(mel_main),
                              hipFuncAttributeMaxDynamicSharedMemorySize, LDS_MAIN);
    mel_main<<<dim3(1024), dim3(512), LDS_MAIN, stream>>>(
        F, W, IDX, MSp, GHp, SSp, OUT);
  } else {
    mel_fallback<<<dim3(NDIM / 8, LDIM), dim3(256), 0, stream>>>(F, MEAN, IC, W, IDX, OUT);
  }
}

// Round 9
// 127.163 us; speedup vs baseline: 1.0530x; 1.0530x over previous
//
#include <hip/hip_runtime.h>
#include <hip/hip_bf16.h>
#include <stdint.h>

// MahalanobisEnsembleLoss: out = sum_l w[l] * mean_n( v^T M_l v ),  v = F[l,n,:] - MEAN[l,idx[n],:]
// R9 decomposition (asymmetry-correct, validated R8):  MS = M + M^T (fp16)
//   q_n = 0.5 f^T MS f  -  f . g[idx_n]  +  s[idx_n]
//   g[c] = MS . mean[c]  (fp16 table),  s[c] = 0.5 mean[c] . g[c]  (fp32 table)
// R9 structure: one-shot burst staging (16 float4/thread in flight -> MLP saturates HBM),
// ONE barrier, then a barrier-free K-loop (A from LDS, B from XCD-L2, TLP-covered).
#define LDIM 4
#define NDIM 16384
#define DDIM 512
#define CDIM 1000
#define BN 64

// ---- workspace layout (bytes) ----
#define MS_ELEMS ((size_t)LDIM * DDIM * DDIM)
#define GH_OFF   (MS_ELEMS * 2)
#define GH_ELEMS ((size_t)LDIM * CDIM * DDIM)
#define SS_OFF   (GH_OFF + GH_ELEMS * 2)
#define SS_FLOATS ((size_t)LDIM * 1024)
#define WS_NEED  (SS_OFF + SS_FLOATS * 4)   // ~5.92 MiB

typedef __attribute__((ext_vector_type(8))) _Float16 f16x8;
typedef __attribute__((ext_vector_type(4))) float f32x4;

__device__ __forceinline__ unsigned short f2h(float x) {
  union { _Float16 h; unsigned short u; } c; c.h = (_Float16)x; return c.u;
}
__device__ __forceinline__ float h2f(unsigned short u) {
  union { unsigned short u; _Float16 h; } c; c.u = u; return (float)c.h;
}
__device__ __forceinline__ f16x8 cvt8(float4 a, float4 b) {
  f16x8 p;
  p[0] = (_Float16)a.x; p[1] = (_Float16)a.y; p[2] = (_Float16)a.z; p[3] = (_Float16)a.w;
  p[4] = (_Float16)b.x; p[5] = (_Float16)b.y; p[6] = (_Float16)b.z; p[7] = (_Float16)b.w;
  return p;
}

// LDS tile [64 rows][512 e] fp16, row stride 1024 B, 16B granule g=(e>>3) XOR'ed with row&7:
//   byte(row,e) = row*1024 + (((e>>3) ^ (row&7))<<4) + (e&7)*2
#define LDS_MAIN (65536 + 256 + 256 + 32)   // VH | ids[64] | svals[64] | red[8]
#define LDS_PREP 65536

// K0: MS = fp16(M + M^T). Coalesced row read + strided transposed read (R1-validated).
extern "C" __global__ void mel_mconv(const float* __restrict__ IC,
                                     unsigned short* __restrict__ MS) {
  size_t i4 = (size_t)blockIdx.x * 256 + threadIdx.x;  // covers L*D*D/4
  size_t base = i4 * 4;
  int l = (int)(base >> 18);
  int rem = (int)(base & 262143);
  int e = rem & 511;
  int d = rem >> 9;
  float4 v = *(const float4*)(IC + base);
  const float* icl = IC + ((size_t)l << 18);
  float t0 = icl[(size_t)(e + 0) * DDIM + d];
  float t1 = icl[(size_t)(e + 1) * DDIM + d];
  float t2 = icl[(size_t)(e + 2) * DDIM + d];
  float t3 = icl[(size_t)(e + 3) * DDIM + d];
  *(ushort4*)(MS + base) = make_ushort4(f2h(v.x + t0), f2h(v.y + t1),
                                        f2h(v.z + t2), f2h(v.w + t3));
}

// K1: G[l,c,:] = fp16(MS . mean[l,c,:]), S[l,c] = 0.5 * meanh . G. 64 blocks x 512 thr.
extern "C" __global__ __launch_bounds__(512, 2)
void mel_prep(const float* __restrict__ MEAN, const unsigned short* __restrict__ MS,
              unsigned short* __restrict__ GH, float* __restrict__ SS) {
  extern __shared__ __align__(16) char lds[];
  const int t = threadIdx.x, lane = t & 63, w = t >> 6;
  const int l = blockIdx.x & 3, ct = blockIdx.x >> 2;
  const int row0 = ct * 64;
  const int col0 = w * 64, lrow = lane & 15, lkg = lane >> 4;
  const int lke = lkg << 3;

  {  // stage all 8 chunks of mean rows as fp16 (rows >= CDIM -> 0)
    const int srow = t >> 3;
    const int grow = row0 + srow;
    const float* mr = MEAN + ((size_t)l * CDIM + grow) * DDIM + ((t & 7) << 3);
    const int swb = srow * 1024 + (((t & 7) ^ (srow & 7)) << 4);
    const float4 z4 = {0.f, 0.f, 0.f, 0.f};
    for (int c = 0; c < 8; ++c) {
      float4 x = z4, y = z4;
      if (grow < CDIM) { x = *(const float4*)(mr + c * 64); y = *(const float4*)(mr + c * 64 + 4); }
      *(f16x8*)(lds + swb + c * 128) = cvt8(x, y);
    }
  }
  __syncthreads();

  const unsigned short* bw = MS + (size_t)l * DDIM * DDIM + (size_t)(col0 + lrow) * DDIM + lke;
  f32x4 acc[4][4];
#pragma unroll
  for (int i = 0; i < 4; ++i)
#pragma unroll
    for (int j = 0; j < 4; ++j) acc[i][j] = {0.f, 0.f, 0.f, 0.f};

  for (int c = 0; c < 8; ++c) {
#pragma unroll
    for (int ks = 0; ks < 2; ++ks) {
      const unsigned short* bc = bw + c * 64 + ks * 32;
      f16x8 b0 = *(const f16x8*)(bc);
      f16x8 b1 = *(const f16x8*)(bc + 16 * DDIM);
      f16x8 b2 = *(const f16x8*)(bc + 32 * DDIM);
      f16x8 b3 = *(const f16x8*)(bc + 48 * DDIM);
      const int xo = c * 128 + ((((ks << 2) + lkg) ^ (lrow & 7)) << 4);
      f16x8 a0 = *(const f16x8*)(lds + lrow * 1024 + xo);
      f16x8 a1 = *(const f16x8*)(lds + (16 + lrow) * 1024 + xo);
      f16x8 a2 = *(const f16x8*)(lds + (32 + lrow) * 1024 + xo);
      f16x8 a3 = *(const f16x8*)(lds + (48 + lrow) * 1024 + xo);
#pragma unroll
      for (int nf = 0; nf < 4; ++nf) {
        f16x8 a = nf == 0 ? a0 : nf == 1 ? a1 : nf == 2 ? a2 : a3;
        acc[nf][0] = __builtin_amdgcn_mfma_f32_16x16x32_f16(a, b0, acc[nf][0], 0, 0, 0);
        acc[nf][1] = __builtin_amdgcn_mfma_f32_16x16x32_f16(a, b1, acc[nf][1], 0, 0, 0);
        acc[nf][2] = __builtin_amdgcn_mfma_f32_16x16x32_f16(a, b2, acc[nf][2], 0, 0, 0);
        acc[nf][3] = __builtin_amdgcn_mfma_f32_16x16x32_f16(a, b3, acc[nf][3], 0, 0, 0);
      }
    }
  }

  // store G (fp16) + per-row S partials (S gets the 0.5 factor)
#pragma unroll
  for (int nf = 0; nf < 4; ++nf)
#pragma unroll
    for (int r = 0; r < 4; ++r) {
      const int nloc = nf * 16 + lkg * 4 + r;
      const int grow = row0 + nloc;
      float sp = 0.f;
#pragma unroll
      for (int df = 0; df < 4; ++df) {
        const int dcol = col0 + df * 16 + lrow;
        const float av = acc[nf][df][r];
        const float mh = h2f(*(const unsigned short*)(
            lds + nloc * 1024 + (((dcol >> 3) ^ (nloc & 7)) << 4) + (dcol & 7) * 2));
        sp += mh * av;
        if (grow < CDIM) GH[((size_t)l * CDIM + grow) * DDIM + dcol] = f2h(av);
      }
      sp += __shfl_xor(sp, 1); sp += __shfl_xor(sp, 2);
      sp += __shfl_xor(sp, 4); sp += __shfl_xor(sp, 8);
      if (lrow == 0 && grow < CDIM) atomicAdd(SS + l * 1024 + grow, 0.5f * sp);
    }
}

// K2 main: burst-staged f^T MS f GEMM + epilogue q = sum fh*(0.5*acc - gh) + s[idx].
// 8 waves; wave = all 64 rows x 64 cols. One barrier total; K-loop barrier-free.
extern "C" __global__ __launch_bounds__(512, 4)
void mel_main(const float* __restrict__ F, const float* __restrict__ W,
              const int* __restrict__ IDX, const unsigned short* __restrict__ MS,
              const unsigned short* __restrict__ GH, const float* __restrict__ SS,
              float* __restrict__ OUT) {
  extern __shared__ __align__(16) char lds[];
  int* ids = (int*)(lds + 65536);
  float* svals = (float*)(lds + 65536 + 256);
  float* red = (float*)(lds + 65536 + 512);
  const int t = threadIdx.x, lane = t & 63, w = t >> 6;
  const int bid = blockIdx.x, xcd = bid & 7, l = xcd >> 1;
  const int bx = ((bid >> 3) << 1) + (xcd & 1);
  const int n0 = bx * BN;
  const int col0 = w * 64, lrow = lane & 15, lkg = lane >> 4;
  const int lke = lkg << 3;

  // ---- one-shot burst staging: 16 float4 loads in flight per thread (MLP)
  const float* fr = F + ((size_t)l * NDIM + n0 + (t >> 3)) * DDIM + ((t & 7) << 3);
  const float4* f4 = (const float4*)fr;
  const int swb = (t >> 3) * 1024 + (((t & 7) ^ ((t >> 3) & 7)) << 4);
  float4 fv[16];
#pragma unroll
  for (int c = 0; c < 8; ++c) {
    fv[2 * c] = f4[c * 16];
    fv[2 * c + 1] = f4[c * 16 + 1];
  }
  if (t < 64) {
    const int cc = IDX[n0 + t];
    ids[t] = cc;
    svals[t] = SS[l * 1024 + cc];
  }
#pragma unroll
  for (int c = 0; c < 8; ++c)
    *(f16x8*)(lds + swb + c * 128) = cvt8(fv[2 * c], fv[2 * c + 1]);
  __syncthreads();  // the ONLY barrier before the epilogue

  const unsigned short* bw = MS + (size_t)l * DDIM * DDIM + (size_t)(col0 + lrow) * DDIM + lke;
  f32x4 acc[4][4];
#pragma unroll
  for (int i = 0; i < 4; ++i)
#pragma unroll
    for (int j = 0; j < 4; ++j) acc[i][j] = {0.f, 0.f, 0.f, 0.f};

  // ---- barrier-free K-loop: A from LDS (read-only), B from XCD-L2
  for (int c = 0; c < 8; ++c) {
#pragma unroll
    for (int ks = 0; ks < 2; ++ks) {
      const unsigned short* bc = bw + c * 64 + ks * 32;
      f16x8 b0 = *(const f16x8*)(bc);
      f16x8 b1 = *(const f16x8*)(bc + 16 * DDIM);
      f16x8 b2 = *(const f16x8*)(bc + 32 * DDIM);
      f16x8 b3 = *(const f16x8*)(bc + 48 * DDIM);
      const int xo = c * 128 + ((((ks << 2) + lkg) ^ (lrow & 7)) << 4);
      f16x8 a0 = *(const f16x8*)(lds + lrow * 1024 + xo);
      f16x8 a1 = *(const f16x8*)(lds + (16 + lrow) * 1024 + xo);
      f16x8 a2 = *(const f16x8*)(lds + (32 + lrow) * 1024 + xo);
      f16x8 a3 = *(const f16x8*)(lds + (48 + lrow) * 1024 + xo);
#pragma unroll
      for (int nf = 0; nf < 4; ++nf) {
        f16x8 a = nf == 0 ? a0 : nf == 1 ? a1 : nf == 2 ? a2 : a3;
        acc[nf][0] = __builtin_amdgcn_mfma_f32_16x16x32_f16(a, b0, acc[nf][0], 0, 0, 0);
        acc[nf][1] = __builtin_amdgcn_mfma_f32_16x16x32_f16(a, b1, acc[nf][1], 0, 0, 0);
        acc[nf][2] = __builtin_amdgcn_mfma_f32_16x16x32_f16(a, b2, acc[nf][2], 0, 0, 0);
        acc[nf][3] = __builtin_amdgcn_mfma_f32_16x16x32_f16(a, b3, acc[nf][3], 0, 0, 0);
      }
    }
  }

  // ---- epilogue: q = sum_d fh*(0.5*acc - gh)  (+ s[idx] once per row, wave 0)
  const unsigned short* gh_l = GH + (size_t)l * CDIM * DDIM;
  float tsum = 0.f;
#pragma unroll
  for (int nf = 0; nf < 4; ++nf)
#pragma unroll
    for (int r = 0; r < 4; ++r) {
      const int row = nf * 16 + lkg * 4 + r;
      const unsigned short* gp = gh_l + (size_t)ids[row] * DDIM;
#pragma unroll
      for (int df = 0; df < 4; ++df) {
        const int dcol = col0 + df * 16 + lrow;
        const float fh = h2f(*(const unsigned short*)(
            lds + row * 1024 + (((dcol >> 3) ^ (row & 7)) << 4) + (dcol & 7) * 2));
        const float gh = h2f(gp[dcol]);
        tsum += fh * (0.5f * acc[nf][df][r] - gh);
      }
      if (w == 0 && lrow == 0) tsum += svals[row];
    }
#pragma unroll
  for (int off = 32; off > 0; off >>= 1) tsum += __shfl_down(tsum, off);
  __syncthreads();
  if (lane == 0) red[w] = tsum;
  __syncthreads();
  if (t == 0) {
    float ssum = 0.f;
#pragma unroll
    for (int i = 0; i < 8; ++i) ssum += red[i];
    atomicAdd(OUT, ssum * (W[l] / (float)NDIM));
  }
}

// Correct-but-slow fp32 fallback (only if ws_size < WS_NEED).
extern "C" __global__ void mel_fallback(const float* __restrict__ F,
                                        const float* __restrict__ MEAN,
                                        const float* __restrict__ IC,
                                        const float* __restrict__ W,
                                        const int* __restrict__ IDX,
                                        float* __restrict__ OUT) {
  __shared__ float v[8][DDIM];
  __shared__ float red[256];
  const int t = threadIdx.x;
  const int l = blockIdx.y;
  const int n0 = blockIdx.x * 8;
  for (int i = t; i < 8 * DDIM; i += 256) {
    int n = i >> 9, e = i & 511;
    int c = IDX[n0 + n];
    v[n][e] = F[((size_t)l * NDIM + n0 + n) * DDIM + e] -
              MEAN[((size_t)l * CDIM + c) * DDIM + e];
  }
  __syncthreads();
  const float* icl = IC + ((size_t)l << 18);
  float part = 0.f;
  for (int rep = 0; rep < 2; ++rep) {
    int d = t + rep * 256;
    float s[8];
#pragma unroll
    for (int j = 0; j < 8; ++j) s[j] = 0.f;
    for (int e = 0; e < DDIM; ++e) {
      float m = icl[(size_t)d * DDIM + e];
#pragma unroll
      for (int j = 0; j < 8; ++j) s[j] += m * v[j][e];
    }
#pragma unroll
    for (int j = 0; j < 8; ++j) part += v[j][d] * s[j];
  }
  red[t] = part;
  __syncthreads();
  for (int o = 128; o > 0; o >>= 1) {
    if (t < o) red[t] += red[t + o];
    __syncthreads();
  }
  if (t == 0) atomicAdd(OUT, red[0] * (W[l] / (float)NDIM));
}

extern "C" void kernel_launch(void* const* d_in, const int* in_sizes, int n_in,
                              void* d_out, int out_size, void* d_ws, size_t ws_size,
                              hipStream_t stream) {
  const float* F = (const float*)d_in[0];
  const float* MEAN = (const float*)d_in[1];
  const float* IC = (const float*)d_in[2];
  const float* W = (const float*)d_in[3];
  const int* IDX = (const int*)d_in[4];
  float* OUT = (float*)d_out;

  hipMemsetAsync(d_out, 0, sizeof(float) * (size_t)out_size, stream);

  if (ws_size >= WS_NEED) {
    unsigned short* MSp = (unsigned short*)d_ws;
    unsigned short* GHp = (unsigned short*)((char*)d_ws + GH_OFF);
    float* SSp = (float*)((char*)d_ws + SS_OFF);
    hipMemsetAsync(SSp, 0, SS_FLOATS * 4, stream);
    mel_mconv<<<dim3(1024), dim3(256), 0, stream>>>(IC, MSp);
    (void)hipFuncSetAttribute(reinterpret_cast<const void*>(mel_prep),
                              hipFuncAttributeMaxDynamicSharedMemorySize, LDS_PREP);
    mel_prep<<<dim3(64), dim3(512), LDS_PREP, stream>>>(MEAN, MSp, GHp, SSp);
    (void)hipFuncSetAttribute(reinterpret_cast<const void*>(mel_main),
                              hipFuncAttributeMaxDynamicSharedMemorySize, LDS_MAIN);
    mel_main<<<dim3(1024), dim3(512), LDS_MAIN, stream>>>(
        F, W, IDX, MSp, GHp, SSp, OUT);
  } else {
    mel_fallback<<<dim3(NDIM / 8, LDIM), dim3(256), 0, stream>>>(F, MEAN, IC, W, IDX, OUT);
  }
}